// Round 4
// baseline (374.167 us; speedup 1.0000x reference)
//
#include <hip/hip_runtime.h>
#include <stdint.h>

#define NUM_CAP 16
#define DIM_CAP 64
#define BATCH   64
#define N_IN    512
#define D_IN    1024
#define N_COL   1024                 // NUM_CAP*DIM_CAP
#define M_ROWS  (BATCH*N_IN)         // 32768

typedef __attribute__((ext_vector_type(8))) short short8;
typedef __attribute__((ext_vector_type(4))) float f32x4;

__device__ __forceinline__ float bf2f(unsigned int u) {
  return __uint_as_float(u << 16);
}
__device__ __forceinline__ unsigned short f2bf_rne(float f) {
  unsigned int x = __float_as_uint(f);
  x += 0x7fffu + ((x >> 16) & 1u);   // RNE
  return (unsigned short)(x >> 16);
}
__device__ __forceinline__ unsigned int pack_trunc(unsigned int lo, unsigned int hi) {
  return (lo >> 16) | (hi & 0xffff0000u);
}

// ---------------------------------------------------------------------------
// W fp32 [D_IN][N_COL] -> Wt bf16 [N_COL][D_IN]  (transpose + RNE convert)
// ---------------------------------------------------------------------------
__global__ void transpose_w(const float* __restrict__ W,
                            unsigned short* __restrict__ Wt) {
  __shared__ float tile[32][33];
  const int tx = threadIdx.x, ty = threadIdx.y;
  const int bx = blockIdx.x, by = blockIdx.y;
  tile[ty][tx] = W[(by * 32 + ty) * N_COL + bx * 32 + tx];
  __syncthreads();
  Wt[(bx * 32 + ty) * D_IN + by * 32 + tx] = f2bf_rne(tile[tx][ty]);
}

// ---------------------------------------------------------------------------
// GEMM: uhat[m][n] = sum_k x[m][k] * Wt[n][k].  A fp32 read directly (128 MB
// once), packed to bf16 in-register during LDS staging. Bt bf16 via
// global_load_lds width=16. XOR-swizzled LDS on BOTH tiles (chunk c of row r
// stored at c^((r>>1)&3)) -> ds bank spread <=2-way (free, m136).
// XCD-aware tile mapping: xcd = blockIdx&7 owns mt in [xcd*32, xcd*32+32) and
// all 8 nt -> the 8 blocks sharing an A-tile land on the SAME XCD's L2, so A
// is fetched from HBM ~once instead of ~4x (round-3 FETCH evidence).
// 128x128 tile, BK=32, 4 waves (2x2), each wave 4x4 of 16x16x32 MFMA.
// ---------------------------------------------------------------------------
__global__ __launch_bounds__(256) void gemm_uhat(
    const float* __restrict__ A,             // [M_ROWS][D_IN] fp32
    const unsigned short* __restrict__ Bt,   // [N_COL][D_IN] bf16
    unsigned short* __restrict__ C) {        // [M_ROWS][N_COL] bf16
  __shared__ __align__(16) unsigned short lA[128 * 32];
  __shared__ __align__(16) unsigned short lB[128 * 32];

  const int t = threadIdx.x;
  const int wave = t >> 6, lane = t & 63;
  // XCD swizzle: same-XCD blocks (idx = x mod 8) sweep nt fastest within a
  // 32-wide private mt slice.
  const int xcd = blockIdx.x & 7, local = blockIdx.x >> 3;
  const int mt = xcd * 32 + (local >> 3), nt = local & 7;
  const int m0 = mt * 128, n0 = nt * 128;
  const int wm = wave & 1, wn = wave >> 1;

  f32x4 acc[4][4] = {};

  // A staging: thread t owns row ar=t>>1, k-half ah=t&1 (16 fp32 = 64 B),
  // writes 2 b128 chunks (global k-chunks 2ah, 2ah+1) at swizzled positions.
  const int ar = t >> 1, ah = t & 1;
  const float* agp = A + (size_t)(m0 + ar) * D_IN + ah * 16;
  const int xrA = (ar >> 1) & 3;
  unsigned short* lap0 = lA + ar * 32 + ((2 * ah + 0) ^ xrA) * 8;
  unsigned short* lap1 = lA + ar * 32 + ((2 * ah + 1) ^ xrA) * 8;

  // B staging via global_load_lds: lane l -> dense dest (base + l*16B);
  // fetch the swizzled-source chunk so position c holds global chunk c^mask.
  const int srow = lane >> 2;
  const int schunk = ((lane & 3) ^ ((srow >> 1) & 3)) * 8;

  for (int kt = 0; kt < D_IN / 32; ++kt) {
    const int k0 = kt * 32;
    __syncthreads();
    // ---- A: 16 fp32 -> 16 bf16 (truncate) -> 2x ds_write_b128 (swizzled)
    const uint4 a0 = *(const uint4*)(agp + k0);
    const uint4 a1 = *(const uint4*)(agp + k0 + 4);
    const uint4 a2 = *(const uint4*)(agp + k0 + 8);
    const uint4 a3 = *(const uint4*)(agp + k0 + 12);
    uint4 p0, p1;
    p0.x = pack_trunc(a0.x, a0.y); p0.y = pack_trunc(a0.z, a0.w);
    p0.z = pack_trunc(a1.x, a1.y); p0.w = pack_trunc(a1.z, a1.w);
    p1.x = pack_trunc(a2.x, a2.y); p1.y = pack_trunc(a2.z, a2.w);
    p1.z = pack_trunc(a3.x, a3.y); p1.w = pack_trunc(a3.z, a3.w);
    *(uint4*)lap0 = p0;
    *(uint4*)lap1 = p1;
    // ---- B: async global->LDS, 8 segments of 16 rows, 2 per wave
    #pragma unroll
    for (int s0 = 0; s0 < 2; ++s0) {
      const int s = wave + s0 * 4;
      const unsigned short* gb = Bt + (size_t)(n0 + s * 16 + srow) * D_IN + k0 + schunk;
      __builtin_amdgcn_global_load_lds(
          (const __attribute__((address_space(1))) void*)gb,
          (__attribute__((address_space(3))) void*)(lB + s * 512), 16, 0, 0);
    }
    __syncthreads();

    short8 af[4], bfr[4];
    const int rsel = lane & 15;
    const int q = lane >> 4;
    const int koff = (q ^ ((rsel >> 1) & 3)) * 8;  // matching read swizzle
    #pragma unroll
    for (int tm = 0; tm < 4; tm++)
      af[tm] = *(const short8*)&lA[(wm * 64 + tm * 16 + rsel) * 32 + koff];
    #pragma unroll
    for (int tn = 0; tn < 4; tn++)
      bfr[tn] = *(const short8*)&lB[(wn * 64 + tn * 16 + rsel) * 32 + koff];
    #pragma unroll
    for (int tm = 0; tm < 4; tm++)
      #pragma unroll
      for (int tn = 0; tn < 4; tn++)
        acc[tm][tn] = __builtin_amdgcn_mfma_f32_16x16x32_bf16(
            af[tm], bfr[tn], acc[tm][tn], 0, 0, 0);
  }

  // Epilogue: C/D layout col=lane&15, row=(lane>>4)*4+reg  [m89-verified]
  const int lrow = (lane >> 4) * 4, lcol = lane & 15;
  #pragma unroll
  for (int tm = 0; tm < 4; tm++)
    #pragma unroll
    for (int tn = 0; tn < 4; tn++)
      #pragma unroll
      for (int r = 0; r < 4; r++) {
        const int row = m0 + wm * 64 + tm * 16 + lrow + r;
        const int col = n0 + wn * 64 + tn * 16 + lcol;
        C[(size_t)row * N_COL + col] = f2bf_rne(acc[tm][tn][r]);
      }
}

// ---------------------------------------------------------------------------
// Routing pass: block = (b, jt4); wave w handles jt = jt4*4+w (8 j's).
// lane l holds u_hat[b, i=l>>2, j, k=(l&3)*16..+16]. Softmax over i via
// xor-{4..32} shuffles; block-reduce 4 waves via LDS -> P[b][jt4][i][k].
// ---------------------------------------------------------------------------
__global__ __launch_bounds__(256) void route_partial(
    const unsigned short* __restrict__ uhat,
    const float* __restrict__ prev,
    float* __restrict__ P,
    const int first) {
  __shared__ float red[4][1024];
  const int t = threadIdx.x;
  const int w = t >> 6, lane = t & 63;
  const int b = blockIdx.x >> 4, jt4 = blockIdx.x & 15;
  const int jt = jt4 * 4 + w;
  const int i_l = lane >> 2, c4 = lane & 3;

  float pv[16];
  if (!first) {
    const float* pp = prev + (b * NUM_CAP + i_l) * DIM_CAP + c4 * 16;
    #pragma unroll
    for (int q = 0; q < 16; q++) pv[q] = pp[q];
  }
  float acc[16];
  #pragma unroll
  for (int q = 0; q < 16; q++) acc[q] = 0.f;

  const unsigned short* ub =
      uhat + (size_t)(b * N_IN + jt * 8) * N_COL + lane * 16;

  for (int jj = 0; jj < 8; ++jj, ub += N_COL) {
    const uint4 d0 = *(const uint4*)ub;
    const uint4 d1 = *(const uint4*)(ub + 8);
    float u[16];
    #define UNP(wd, o) { u[(o)] = bf2f((wd) & 0xffffu); u[(o)+1] = __uint_as_float((wd) & 0xffff0000u); }
    UNP(d0.x, 0) UNP(d0.y, 2) UNP(d0.z, 4) UNP(d0.w, 6)
    UNP(d1.x, 8) UNP(d1.y, 10) UNP(d1.z, 12) UNP(d1.w, 14)
    #undef UNP

    float c;
    if (first) {
      c = 0.0625f;
    } else {
      float dot = 0.f;
      #pragma unroll
      for (int q = 0; q < 16; q++) dot = fmaf(pv[q], u[q], dot);
      dot += __shfl_xor(dot, 1);
      dot += __shfl_xor(dot, 2);
      float m = dot;
      #pragma unroll
      for (int d = 4; d < 64; d <<= 1) m = fmaxf(m, __shfl_xor(m, d));
      const float e = __expf(dot - m);
      float s = e;
      #pragma unroll
      for (int d = 4; d < 64; d <<= 1) s += __shfl_xor(s, d);
      c = e / s;
    }
    #pragma unroll
    for (int q = 0; q < 16; q++) acc[q] = fmaf(c, u[q], acc[q]);
  }

  #pragma unroll
  for (int q = 0; q < 4; q++)
    *(float4*)&red[w][lane * 16 + q * 4] = make_float4(
        acc[q * 4 + 0], acc[q * 4 + 1], acc[q * 4 + 2], acc[q * 4 + 3]);
  __syncthreads();
  const float4 r0 = *(const float4*)&red[0][t * 4];
  const float4 r1 = *(const float4*)&red[1][t * 4];
  const float4 r2 = *(const float4*)&red[2][t * 4];
  const float4 r3 = *(const float4*)&red[3][t * 4];
  float4 s;
  s.x = r0.x + r1.x + r2.x + r3.x;
  s.y = r0.y + r1.y + r2.y + r3.y;
  s.z = r0.z + r1.z + r2.z + r3.z;
  s.w = r0.w + r1.w + r2.w + r3.w;
  *(float4*)&P[(size_t)blockIdx.x * 1024 + t * 4] = s;
}

// ---------------------------------------------------------------------------
__global__ __launch_bounds__(64) void route_reduce(
    const float* __restrict__ P, float* __restrict__ dst) {
  const int bi = blockIdx.x;
  const int k = threadIdx.x;
  const int b = bi >> 4, i = bi & 15;
  const float* p = P + (size_t)b * 16 * 1024 + i * 64 + k;
  float s = 0.f;
  #pragma unroll
  for (int tt = 0; tt < 16; ++tt) s += p[(size_t)tt * 1024];
  float ss = s * s;
  #pragma unroll
  for (int d = 1; d < 64; d <<= 1) ss += __shfl_xor(ss, d);
  dst[bi * 64 + k] = s / sqrtf(ss + 1e-7f);
}

// ---------------------------------------------------------------------------
extern "C" void kernel_launch(void* const* d_in, const int* in_sizes, int n_in,
                              void* d_out, int out_size, void* d_ws, size_t ws_size,
                              hipStream_t stream) {
  const float* x = (const float*)d_in[0];   // [64][512][1024] fp32
  const float* W = (const float*)d_in[1];   // [1][1024][1024] fp32
  float* out = (float*)d_out;               // [64][16][64] fp32

  char* ws = (char*)d_ws;
  unsigned short* Wt   = (unsigned short*)ws;                        // 0..2 MB
  unsigned short* uhat = (unsigned short*)(ws + (size_t)(2 << 20));  // 2..66 MB
  float* P    = (float*)(ws + (size_t)66 * (1 << 20));               // 66..70 MB
  float* prev = (float*)(ws + (size_t)70 * (1 << 20));               // 70..70.25

  transpose_w<<<dim3(32, 32), dim3(32, 32), 0, stream>>>(W, Wt);
  gemm_uhat<<<2048, 256, 0, stream>>>(x, Wt, uhat);

  route_partial<<<1024, 256, 0, stream>>>(uhat, prev, P, 1);
  route_reduce<<<1024, 64, 0, stream>>>(P, prev);
  route_partial<<<1024, 256, 0, stream>>>(uhat, prev, P, 0);
  route_reduce<<<1024, 64, 0, stream>>>(P, prev);
  route_partial<<<1024, 256, 0, stream>>>(uhat, prev, P, 0);
  route_reduce<<<1024, 64, 0, stream>>>(P, out);
}

// Round 5
// 371.900 us; speedup vs baseline: 1.0061x; 1.0061x over previous
//
#include <hip/hip_runtime.h>
#include <stdint.h>

#define NUM_CAP 16
#define DIM_CAP 64
#define BATCH   64
#define N_IN    512
#define D_IN    1024
#define N_COL   1024                 // NUM_CAP*DIM_CAP
#define M_ROWS  (BATCH*N_IN)         // 32768

typedef __attribute__((ext_vector_type(8))) short short8;
typedef __attribute__((ext_vector_type(4))) float f32x4;

__device__ __forceinline__ float bf2f(unsigned int u) {
  return __uint_as_float(u << 16);
}
__device__ __forceinline__ unsigned short f2bf_rne(float f) {
  unsigned int x = __float_as_uint(f);
  x += 0x7fffu + ((x >> 16) & 1u);   // RNE
  return (unsigned short)(x >> 16);
}
__device__ __forceinline__ unsigned int pack_trunc(unsigned int lo, unsigned int hi) {
  return (lo >> 16) | (hi & 0xffff0000u);
}

// ---------------------------------------------------------------------------
// W fp32 [D_IN][N_COL] -> Wt bf16 [N_COL][D_IN]  (transpose + RNE convert)
// ---------------------------------------------------------------------------
__global__ void transpose_w(const float* __restrict__ W,
                            unsigned short* __restrict__ Wt) {
  __shared__ float tile[32][33];
  const int tx = threadIdx.x, ty = threadIdx.y;
  const int bx = blockIdx.x, by = blockIdx.y;
  tile[ty][tx] = W[(by * 32 + ty) * N_COL + bx * 32 + tx];
  __syncthreads();
  Wt[(bx * 32 + ty) * D_IN + by * 32 + tx] = f2bf_rne(tile[tx][ty]);
}

// ---------------------------------------------------------------------------
// GEMM: uhat[m][n] = sum_k x[m][k] * Wt[n][k].
// A fp32 read via SOFTWARE-PIPELINED register prefetch: loads for tile kt+1
// are issued in the compute phase of tile kt (they drain at the next top
// barrier, hidden under ds_read+MFMA) -- round-4 evidence showed the
// non-pipelined fp32 staging chain was the 193 us bottleneck (HBM 10%,
// MfmaUtil 14% => latency-bound).  Bt via global_load_lds width=16.
// XOR-swizzled LDS on both tiles (bank spread <=2-way, R3: conflicts=0).
// XCD-aware mapping (R4: FETCH 265->90 MB): xcd=blockIdx&7 owns a 32-wide mt
// slice, nt sweeps fastest -> A-tile sharers land on the same XCD's L2.
// ---------------------------------------------------------------------------
__global__ __launch_bounds__(256) void gemm_uhat(
    const float* __restrict__ A,             // [M_ROWS][D_IN] fp32
    const unsigned short* __restrict__ Bt,   // [N_COL][D_IN] bf16
    unsigned short* __restrict__ C) {        // [M_ROWS][N_COL] bf16
  __shared__ __align__(16) unsigned short lA[128 * 32];
  __shared__ __align__(16) unsigned short lB[128 * 32];

  const int t = threadIdx.x;
  const int wave = t >> 6, lane = t & 63;
  const int xcd = blockIdx.x & 7, local = blockIdx.x >> 3;
  const int mt = xcd * 32 + (local >> 3), nt = local & 7;
  const int m0 = mt * 128, n0 = nt * 128;
  const int wm = wave & 1, wn = wave >> 1;

  f32x4 acc[4][4] = {};

  // A staging: thread t owns row ar=t>>1, k-half ah=t&1 (16 fp32 = 64 B),
  // writes 2 b128 chunks (global k-chunks 2ah, 2ah+1) at swizzled positions.
  const int ar = t >> 1, ah = t & 1;
  const float* agp = A + (size_t)(m0 + ar) * D_IN + ah * 16;
  const int xrA = (ar >> 1) & 3;
  unsigned short* lap0 = lA + ar * 32 + ((2 * ah + 0) ^ xrA) * 8;
  unsigned short* lap1 = lA + ar * 32 + ((2 * ah + 1) ^ xrA) * 8;

  // B staging via global_load_lds: lane l -> dense dest (base + l*16B);
  // fetch the swizzled-source chunk so position c holds global chunk c^mask.
  const int srow = lane >> 2;
  const int schunk = ((lane & 3) ^ ((srow >> 1) & 3)) * 8;

  // ---- prefetch A for kt=0
  uint4 a0 = *(const uint4*)(agp);
  uint4 a1 = *(const uint4*)(agp + 4);
  uint4 a2 = *(const uint4*)(agp + 8);
  uint4 a3 = *(const uint4*)(agp + 12);

  for (int kt = 0; kt < D_IN / 32; ++kt) {
    const int k0 = kt * 32;
    __syncthreads();                 // drains prefetched A loads (vmcnt 0)
    // ---- A: pack prefetched regs -> 2x ds_write_b128 (swizzled)
    uint4 p0, p1;
    p0.x = pack_trunc(a0.x, a0.y); p0.y = pack_trunc(a0.z, a0.w);
    p0.z = pack_trunc(a1.x, a1.y); p0.w = pack_trunc(a1.z, a1.w);
    p1.x = pack_trunc(a2.x, a2.y); p1.y = pack_trunc(a2.z, a2.w);
    p1.z = pack_trunc(a3.x, a3.y); p1.w = pack_trunc(a3.z, a3.w);
    *(uint4*)lap0 = p0;
    *(uint4*)lap1 = p1;
    // ---- B: async global->LDS, 8 segments of 16 rows, 2 per wave
    #pragma unroll
    for (int s0 = 0; s0 < 2; ++s0) {
      const int s = wave + s0 * 4;
      const unsigned short* gb = Bt + (size_t)(n0 + s * 16 + srow) * D_IN + k0 + schunk;
      __builtin_amdgcn_global_load_lds(
          (const __attribute__((address_space(1))) void*)gb,
          (__attribute__((address_space(3))) void*)(lB + s * 512), 16, 0, 0);
    }
    __syncthreads();

    // ---- issue A prefetch for kt+1 (overlaps the MFMA phase below; wraps
    // harmlessly to kt=0 on the last iteration)
    const int kn = ((kt + 1) & 31) * 32;
    a0 = *(const uint4*)(agp + kn);
    a1 = *(const uint4*)(agp + kn + 4);
    a2 = *(const uint4*)(agp + kn + 8);
    a3 = *(const uint4*)(agp + kn + 12);

    short8 af[4], bfr[4];
    const int rsel = lane & 15;
    const int q = lane >> 4;
    const int koff = (q ^ ((rsel >> 1) & 3)) * 8;  // matching read swizzle
    #pragma unroll
    for (int tm = 0; tm < 4; tm++)
      af[tm] = *(const short8*)&lA[(wm * 64 + tm * 16 + rsel) * 32 + koff];
    #pragma unroll
    for (int tn = 0; tn < 4; tn++)
      bfr[tn] = *(const short8*)&lB[(wn * 64 + tn * 16 + rsel) * 32 + koff];
    #pragma unroll
    for (int tm = 0; tm < 4; tm++)
      #pragma unroll
      for (int tn = 0; tn < 4; tn++)
        acc[tm][tn] = __builtin_amdgcn_mfma_f32_16x16x32_bf16(
            af[tm], bfr[tn], acc[tm][tn], 0, 0, 0);
  }

  // Epilogue: C/D layout col=lane&15, row=(lane>>4)*4+reg  [m89-verified]
  const int lrow = (lane >> 4) * 4, lcol = lane & 15;
  #pragma unroll
  for (int tm = 0; tm < 4; tm++)
    #pragma unroll
    for (int tn = 0; tn < 4; tn++)
      #pragma unroll
      for (int r = 0; r < 4; r++) {
        const int row = m0 + wm * 64 + tm * 16 + lrow + r;
        const int col = n0 + wn * 64 + tn * 16 + lcol;
        C[(size_t)row * N_COL + col] = f2bf_rne(acc[tm][tn][r]);
      }
}

// ---------------------------------------------------------------------------
// Fused routing: ONE kernel, one block per batch element b (1024 threads =
// 16 waves), all 3 routing iterations internally.  Wave w covers j =
// w*32..w*32+31; lane l holds u_hat[b, i=l>>2, j, k=(l&3)*16..+16].
// Per iteration: dot with prev-out (quad shuffle), softmax over i
// (xor-{4..32} shuffles), accumulate c*u; LDS-reduce over 16 waves; squash
// in-block (thread t owns (i=t>>6, k=t&63), wave-reduce ||v||^2).
// uhat slice (1 MB/block) stays L2/L3-warm across the 3 passes; no P/prev
// round-trips through HBM (round-4 evidence: 6-dispatch routing ~175 us).
// ---------------------------------------------------------------------------
__global__ __launch_bounds__(1024) void route_all(
    const unsigned short* __restrict__ uhat,  // [M_ROWS][N_COL] bf16
    float* __restrict__ out) {                // [BATCH][16][64] fp32
  __shared__ float red[16][1028];   // +4 pad (reads are per-instr consecutive;
                                    // pad keeps the 16 strided reads 2-way max)
  __shared__ float sq[16][68];      // squashed outputs, padded rows
  const int t = threadIdx.x;
  const int w = t >> 6, lane = t & 63;
  const int b = blockIdx.x;
  const int i_l = lane >> 2, c4 = lane & 3;
  const int oi = t >> 6, ok = t & 63;         // ownership in reduce phase

  const unsigned short* ub0 =
      uhat + (size_t)(b * N_IN + w * 32) * N_COL + lane * 16;

  for (int it = 0; it < 3; ++it) {
    float pv[16];
    if (it) {
      #pragma unroll
      for (int q = 0; q < 4; q++)
        *(float4*)&pv[q * 4] = *(const float4*)&sq[i_l][c4 * 16 + q * 4];
    }
    float acc[16];
    #pragma unroll
    for (int q = 0; q < 16; q++) acc[q] = 0.f;

    const unsigned short* ub = ub0;
    for (int jj = 0; jj < 32; ++jj, ub += N_COL) {
      const uint4 d0 = *(const uint4*)ub;
      const uint4 d1 = *(const uint4*)(ub + 8);
      float u[16];
      #define UNP(wd, o) { u[(o)] = bf2f((wd) & 0xffffu); u[(o)+1] = __uint_as_float((wd) & 0xffff0000u); }
      UNP(d0.x, 0) UNP(d0.y, 2) UNP(d0.z, 4) UNP(d0.w, 6)
      UNP(d1.x, 8) UNP(d1.y, 10) UNP(d1.z, 12) UNP(d1.w, 14)
      #undef UNP

      float c;
      if (it == 0) {
        c = 0.0625f;                // softmax of zeros over 16 capsules
      } else {
        float dot = 0.f;
        #pragma unroll
        for (int q = 0; q < 16; q++) dot = fmaf(pv[q], u[q], dot);
        dot += __shfl_xor(dot, 1);  // reduce over k-quarters -> b_i on quad
        dot += __shfl_xor(dot, 2);
        float m = dot;
        #pragma unroll
        for (int d = 4; d < 64; d <<= 1) m = fmaxf(m, __shfl_xor(m, d));
        const float e = __expf(dot - m);
        float s = e;
        #pragma unroll
        for (int d = 4; d < 64; d <<= 1) s += __shfl_xor(s, d);
        c = e / s;
      }
      #pragma unroll
      for (int q = 0; q < 16; q++) acc[q] = fmaf(c, u[q], acc[q]);
    }

    // stage per-wave partials: wave w's element (i_l, c4*16+q) at
    // red[w][i_l*64 + c4*16 + q]
    #pragma unroll
    for (int q = 0; q < 4; q++)
      *(float4*)&red[w][i_l * 64 + c4 * 16 + q * 4] = make_float4(
          acc[q * 4 + 0], acc[q * 4 + 1], acc[q * 4 + 2], acc[q * 4 + 3]);
    __syncthreads();

    // thread t sums its element over the 16 waves
    float s = 0.f;
    #pragma unroll
    for (int ww = 0; ww < 16; ++ww) s += red[ww][t];

    // squash: ||s_i||^2 over k (wave = capsule i here: oi == w)
    float ss = s * s;
    #pragma unroll
    for (int d = 1; d < 64; d <<= 1) ss += __shfl_xor(ss, d);
    const float v = s / sqrtf(ss + 1e-7f);

    __syncthreads();                // red reads done; sq safe to overwrite
    if (it < 2) {
      sq[oi][ok] = v;
      __syncthreads();              // sq visible before next iteration's read
    } else {
      out[b * 1024 + t] = v;
    }
  }
}

// ---------------------------------------------------------------------------
extern "C" void kernel_launch(void* const* d_in, const int* in_sizes, int n_in,
                              void* d_out, int out_size, void* d_ws, size_t ws_size,
                              hipStream_t stream) {
  const float* x = (const float*)d_in[0];   // [64][512][1024] fp32
  const float* W = (const float*)d_in[1];   // [1][1024][1024] fp32
  float* out = (float*)d_out;               // [64][16][64] fp32

  char* ws = (char*)d_ws;
  unsigned short* Wt   = (unsigned short*)ws;                        // 0..2 MB
  unsigned short* uhat = (unsigned short*)(ws + (size_t)(2 << 20));  // 2..66 MB

  transpose_w<<<dim3(32, 32), dim3(32, 32), 0, stream>>>(W, Wt);
  gemm_uhat<<<2048, 256, 0, stream>>>(x, Wt, uhat);
  route_all<<<BATCH, 1024, 0, stream>>>(uhat, out);
}

// Round 6
// 339.177 us; speedup vs baseline: 1.1032x; 1.0965x over previous
//
#include <hip/hip_runtime.h>
#include <stdint.h>

#define NUM_CAP 16
#define DIM_CAP 64
#define BATCH   64
#define N_IN    512
#define D_IN    1024
#define N_COL   1024
#define M_ROWS  (BATCH*N_IN)

typedef __attribute__((ext_vector_type(8))) short short8;
typedef __attribute__((ext_vector_type(4))) float f32x4;

__device__ __forceinline__ float bf2f(unsigned int u) {
  return __uint_as_float(u << 16);
}
__device__ __forceinline__ unsigned short f2bf_rne(float f) {
  unsigned int x = __float_as_uint(f);
  x += 0x7fffu + ((x >> 16) & 1u);
  return (unsigned short)(x >> 16);
}
__device__ __forceinline__ unsigned int pack_rne(unsigned int lo, unsigned int hi) {
  const unsigned int lr = lo + (0x7fffu + ((lo >> 16) & 1u));
  const unsigned int hr = hi + (0x7fffu + ((hi >> 16) & 1u));
  return (lr >> 16) | (hr & 0xffff0000u);
}

// x fp32 -> bf16 (RNE), 8 elems/thread, coalesced.
__global__ __launch_bounds__(256) void conv_x(const float* __restrict__ x,
                                              unsigned short* __restrict__ xb) {
  const size_t i = ((size_t)blockIdx.x * 256 + threadIdx.x) * 8;
  const uint4 a = *(const uint4*)(x + i);
  const uint4 b = *(const uint4*)(x + i + 4);
  uint4 p;
  p.x = pack_rne(a.x, a.y); p.y = pack_rne(a.z, a.w);
  p.z = pack_rne(b.x, b.y); p.w = pack_rne(b.z, b.w);
  *(uint4*)(xb + i) = p;
}

// W fp32 [D_IN][N_COL] -> Wt bf16 [N_COL][D_IN]
__global__ void transpose_w(const float* __restrict__ W,
                            unsigned short* __restrict__ Wt) {
  __shared__ float tile[32][33];
  const int tx = threadIdx.x, ty = threadIdx.y;
  const int bx = blockIdx.x, by = blockIdx.y;
  tile[ty][tx] = W[(by * 32 + ty) * N_COL + bx * 32 + tx];
  __syncthreads();
  Wt[(bx * 32 + ty) * D_IN + by * 32 + tx] = f2bf_rne(tile[tx][ty]);
}

__global__ __launch_bounds__(256) void zero_s1(float* __restrict__ S1) {
  *(float4*)(S1 + ((size_t)blockIdx.x * 256 + threadIdx.x) * 4) =
      make_float4(0.f, 0.f, 0.f, 0.f);
}

// GEMM (R3 structure: both operands bf16 via global_load_lds w=16, swizzled
// LDS, conflicts=0) + XCD map (R4: A fetched ~once) + fused routing iter-1
// (S1[b][n] += (1/16) * column sums) in epilogue.
__global__ __launch_bounds__(256) void gemm_uhat(
    const unsigned short* __restrict__ A,
    const unsigned short* __restrict__ Bt,
    unsigned short* __restrict__ C,
    float* __restrict__ S1) {
  __shared__ __align__(16) unsigned short lA[128 * 32];
  __shared__ __align__(16) unsigned short lB[128 * 32];
  __shared__ float cs[128];

  const int t = threadIdx.x;
  const int wave = t >> 6, lane = t & 63;
  const int xcd = blockIdx.x & 7, local = blockIdx.x >> 3;
  const int mt = xcd * 32 + (local >> 3), nt = local & 7;
  const int m0 = mt * 128, n0 = nt * 128;
  const int wm = wave & 1, wn = wave >> 1;

  if (t < 128) cs[t] = 0.f;  // K-loop barriers make this visible pre-epilogue

  f32x4 acc[4][4] = {};

  const int srow = lane >> 2;
  const int schunk = ((lane & 3) ^ ((srow >> 1) & 3)) * 8;  // swizzled source chunk

  for (int kt = 0; kt < D_IN / 32; ++kt) {
    const int k0 = kt * 32;
    __syncthreads();
    #pragma unroll
    for (int s0 = 0; s0 < 2; ++s0) {
      const int s = wave + s0 * 4;
      const unsigned short* ga = A + (size_t)(m0 + s * 16 + srow) * D_IN + k0 + schunk;
      __builtin_amdgcn_global_load_lds(
          (const __attribute__((address_space(1))) void*)ga,
          (__attribute__((address_space(3))) void*)(lA + s * 512), 16, 0, 0);
      const unsigned short* gb = Bt + (size_t)(n0 + s * 16 + srow) * D_IN + k0 + schunk;
      __builtin_amdgcn_global_load_lds(
          (const __attribute__((address_space(1))) void*)gb,
          (__attribute__((address_space(3))) void*)(lB + s * 512), 16, 0, 0);
    }
    __syncthreads();

    short8 af[4], bfr[4];
    const int rsel = lane & 15;
    const int q = lane >> 4;
    const int koff = (q ^ ((rsel >> 1) & 3)) * 8;
    #pragma unroll
    for (int tm = 0; tm < 4; tm++)
      af[tm] = *(const short8*)&lA[(wm * 64 + tm * 16 + rsel) * 32 + koff];
    #pragma unroll
    for (int tn = 0; tn < 4; tn++)
      bfr[tn] = *(const short8*)&lB[(wn * 64 + tn * 16 + rsel) * 32 + koff];
    #pragma unroll
    for (int tm = 0; tm < 4; tm++)
      #pragma unroll
      for (int tn = 0; tn < 4; tn++)
        acc[tm][tn] = __builtin_amdgcn_mfma_f32_16x16x32_bf16(
            af[tm], bfr[tn], acc[tm][tn], 0, 0, 0);
  }

  const int lrow = (lane >> 4) * 4, lcol = lane & 15;
  #pragma unroll
  for (int tm = 0; tm < 4; tm++)
    #pragma unroll
    for (int tn = 0; tn < 4; tn++)
      #pragma unroll
      for (int r = 0; r < 4; r++) {
        const int row = m0 + wm * 64 + tm * 16 + lrow + r;
        const int col = n0 + wn * 64 + tn * 16 + lcol;
        C[(size_t)row * N_COL + col] = f2bf_rne(acc[tm][tn][r]);
      }

  // fused routing iter-1 column sums
  #pragma unroll
  for (int tn = 0; tn < 4; tn++) {
    float p = 0.f;
    #pragma unroll
    for (int tm = 0; tm < 4; tm++)
      #pragma unroll
      for (int r = 0; r < 4; r++) p += acc[tm][tn][r];
    atomicAdd(&cs[wn * 64 + tn * 16 + lcol], p);
  }
  __syncthreads();
  if (t < 128)
    atomicAdd(&S1[(size_t)(mt >> 2) * N_COL + n0 + t], cs[t] * 0.0625f);
}

// Routing iteration (it>=1): block=(b,jt4); phase A: redundant reduce+squash
// of previous s (mode 0: S1 plane; mode 1: 16 P-slices); phase B: 8 j's/wave,
// softmax over i (no max-subtract; |b| bounded), 4-wave LDS reduce -> Pout.
__global__ __launch_bounds__(256) void route_mid(
    const unsigned short* __restrict__ uhat,
    const float* __restrict__ Vin,
    float* __restrict__ Pout,
    const int mode) {
  __shared__ float sq[16 * 68];
  __shared__ float red[4][1024];
  const int t = threadIdx.x;
  const int w = t >> 6, lane = t & 63;
  const int b = blockIdx.x >> 4, jt4 = blockIdx.x & 15;
  const int jt = jt4 * 4 + w;
  const int i_l = lane >> 2, c4 = lane & 3;

  float4 v4;
  if (mode == 0) {
    v4 = *(const float4*)&Vin[(size_t)b * 1024 + t * 4];
  } else {
    v4 = make_float4(0.f, 0.f, 0.f, 0.f);
    #pragma unroll
    for (int s = 0; s < 16; ++s) {
      const float4 ps = *(const float4*)&Vin[((size_t)b * 16 + s) * 1024 + t * 4];
      v4.x += ps.x; v4.y += ps.y; v4.z += ps.z; v4.w += ps.w;
    }
  }
  float ss = v4.x * v4.x + v4.y * v4.y + v4.z * v4.z + v4.w * v4.w;
  #pragma unroll
  for (int d = 1; d < 16; d <<= 1) ss += __shfl_xor(ss, d);
  const float inv = 1.f / sqrtf(ss + 1e-7f);
  const int oi = t >> 4, ok = (t & 15) * 4;
  *(float4*)&sq[oi * 68 + ok] = make_float4(v4.x * inv, v4.y * inv, v4.z * inv, v4.w * inv);
  __syncthreads();

  float pv[16];
  #pragma unroll
  for (int q = 0; q < 4; q++)
    *(float4*)&pv[q * 4] = *(const float4*)&sq[i_l * 68 + c4 * 16 + q * 4];

  float acc[16];
  #pragma unroll
  for (int q = 0; q < 16; q++) acc[q] = 0.f;

  const unsigned short* ub =
      uhat + (size_t)(b * N_IN + jt * 8) * N_COL + lane * 16;

  for (int jj = 0; jj < 8; ++jj, ub += N_COL) {
    const uint4 d0 = *(const uint4*)ub;
    const uint4 d1 = *(const uint4*)(ub + 8);
    float u[16];
    #define UNP(wd, o) { u[(o)] = bf2f((wd) & 0xffffu); u[(o)+1] = __uint_as_float((wd) & 0xffff0000u); }
    UNP(d0.x, 0) UNP(d0.y, 2) UNP(d0.z, 4) UNP(d0.w, 6)
    UNP(d1.x, 8) UNP(d1.y, 10) UNP(d1.z, 12) UNP(d1.w, 14)
    #undef UNP

    float dot = 0.f;
    #pragma unroll
    for (int q = 0; q < 16; q++) dot = fmaf(pv[q], u[q], dot);
    dot += __shfl_xor(dot, 1);
    dot += __shfl_xor(dot, 2);
    const float e = __expf(dot);
    float s = e;
    #pragma unroll
    for (int d = 4; d < 64; d <<= 1) s += __shfl_xor(s, d);
    const float c = e / s;
    #pragma unroll
    for (int q = 0; q < 16; q++) acc[q] = fmaf(c, u[q], acc[q]);
  }

  #pragma unroll
  for (int q = 0; q < 4; q++)
    *(float4*)&red[w][lane * 16 + q * 4] = make_float4(
        acc[q * 4 + 0], acc[q * 4 + 1], acc[q * 4 + 2], acc[q * 4 + 3]);
  __syncthreads();
  float4 s4 = make_float4(0.f, 0.f, 0.f, 0.f);
  #pragma unroll
  for (int ww = 0; ww < 4; ++ww) {
    const float4 r = *(const float4*)&red[ww][t * 4];
    s4.x += r.x; s4.y += r.y; s4.z += r.z; s4.w += r.w;
  }
  *(float4*)&Pout[(size_t)blockIdx.x * 1024 + t * 4] = s4;
}

__global__ __launch_bounds__(64) void route_last(
    const float* __restrict__ P, float* __restrict__ dst) {
  const int bi = blockIdx.x;
  const int k = threadIdx.x;
  const int b = bi >> 4, i = bi & 15;
  const float* p = P + (size_t)b * 16 * 1024 + i * 64 + k;
  float s = 0.f;
  #pragma unroll
  for (int tt = 0; tt < 16; ++tt) s += p[(size_t)tt * 1024];
  float ss = s * s;
  #pragma unroll
  for (int d = 1; d < 64; d <<= 1) ss += __shfl_xor(ss, d);
  dst[bi * 64 + k] = s / sqrtf(ss + 1e-7f);
}

extern "C" void kernel_launch(void* const* d_in, const int* in_sizes, int n_in,
                              void* d_out, int out_size, void* d_ws, size_t ws_size,
                              hipStream_t stream) {
  const float* x = (const float*)d_in[0];
  const float* W = (const float*)d_in[1];
  float* out = (float*)d_out;

  char* ws = (char*)d_ws;
  unsigned short* Wt   = (unsigned short*)ws;                            // 0..2 MB
  unsigned short* uhat = (unsigned short*)(ws + (size_t)(2 << 20));      // 2..66 MB
  unsigned short* xb   = (unsigned short*)(ws + (size_t)66 * (1 << 20)); // 66..130 MB (dead after gemm)
  float* S1 = (float*)(ws + (size_t)130 * (1 << 20));                    // 130..130.25 MB
  float* P1 = (float*)(ws + (size_t)66 * (1 << 20));   // reuses dead xb region
  float* P2 = (float*)(ws + (size_t)71 * (1 << 20));   // reuses dead xb region

  transpose_w<<<dim3(32, 32), dim3(32, 32), 0, stream>>>(W, Wt);
  conv_x<<<16384, 256, 0, stream>>>(x, xb);
  zero_s1<<<64, 256, 0, stream>>>(S1);
  gemm_uhat<<<2048, 256, 0, stream>>>(xb, Wt, uhat, S1);

  route_mid<<<1024, 256, 0, stream>>>(uhat, S1, P1, 0);  // routing iter 2
  route_mid<<<1024, 256, 0, stream>>>(uhat, P1, P2, 1);  // routing iter 3
  route_last<<<1024, 64, 0, stream>>>(P2, out);
}

// Round 7
// 322.496 us; speedup vs baseline: 1.1602x; 1.0517x over previous
//
#include <hip/hip_runtime.h>
#include <stdint.h>

#define NUM_CAP 16
#define DIM_CAP 64
#define BATCH   64
#define N_IN    512
#define D_IN    1024
#define N_COL   1024
#define M_ROWS  (BATCH*N_IN)

typedef __attribute__((ext_vector_type(8))) short short8;
typedef __attribute__((ext_vector_type(4))) float f32x4;

__device__ __forceinline__ float bf2f(unsigned int u) {
  return __uint_as_float(u << 16);
}
__device__ __forceinline__ unsigned short f2bf_rne(float f) {
  unsigned int x = __float_as_uint(f);
  x += 0x7fffu + ((x >> 16) & 1u);
  return (unsigned short)(x >> 16);
}
__device__ __forceinline__ unsigned int pack_rne(unsigned int lo, unsigned int hi) {
  const unsigned int lr = lo + (0x7fffu + ((lo >> 16) & 1u));
  const unsigned int hr = hi + (0x7fffu + ((hi >> 16) & 1u));
  return (lr >> 16) | (hr & 0xffff0000u);
}

// ---------------------------------------------------------------------------
// prep: blocks [0,16384) convert x fp32->bf16 (8 elems/thread, coalesced);
// blocks [16384, 16384+1024) transpose+convert W -> Wt[n][k].
// ---------------------------------------------------------------------------
__global__ __launch_bounds__(256) void prep(
    const float* __restrict__ x, const float* __restrict__ W,
    unsigned short* __restrict__ xb, unsigned short* __restrict__ Wt) {
  const int t = threadIdx.x;
  if (blockIdx.x < 16384) {
    const size_t i = ((size_t)blockIdx.x * 256 + t) * 8;
    const uint4 a = *(const uint4*)(x + i);
    const uint4 b = *(const uint4*)(x + i + 4);
    uint4 p;
    p.x = pack_rne(a.x, a.y); p.y = pack_rne(a.z, a.w);
    p.z = pack_rne(b.x, b.y); p.w = pack_rne(b.z, b.w);
    *(uint4*)(xb + i) = p;
  } else {
    __shared__ float tile[32][33];
    const int bid = blockIdx.x - 16384;       // 0..1023
    const int bx = bid & 31, by = bid >> 5;   // 32x32 tiles
    const int tx = t & 31, ty0 = t >> 5;      // 8 rows per pass
    #pragma unroll
    for (int r = 0; r < 4; r++) {
      const int ty = ty0 + r * 8;
      tile[ty][tx] = W[(size_t)(by * 32 + ty) * N_COL + bx * 32 + tx];
    }
    __syncthreads();
    #pragma unroll
    for (int r = 0; r < 4; r++) {
      const int ty = ty0 + r * 8;
      Wt[(size_t)(bx * 32 + ty) * D_IN + by * 32 + tx] = f2bf_rne(tile[tx][ty]);
    }
  }
}

// ---------------------------------------------------------------------------
// GEMM — exactly the R3-measured structure (108 us, VGPR 72, conflicts 0):
// both operands bf16 via global_load_lds width=16, XOR-swizzled LDS
// (position chunk c of row r holds global chunk c^((r>>1)&3)), plus the
// R4/R6-measured XCD map (FETCH 265->65 MB): xcd=blockIdx&7 owns mt in
// [xcd*32,+32), nt sweeps fastest so A-tile sharers hit the same XCD L2.
// NO fused epilogue extras (R6 evidence: S1 fusion cost VGPR 72->100,
// occupancy 28->21%, gemm 108->121 us).
// ---------------------------------------------------------------------------
__global__ __launch_bounds__(256) void gemm_uhat(
    const unsigned short* __restrict__ A,    // [M_ROWS][D_IN] bf16
    const unsigned short* __restrict__ Bt,   // [N_COL][D_IN] bf16
    unsigned short* __restrict__ C) {        // [M_ROWS][N_COL] bf16
  __shared__ __align__(16) unsigned short lA[128 * 32];
  __shared__ __align__(16) unsigned short lB[128 * 32];

  const int t = threadIdx.x;
  const int wave = t >> 6, lane = t & 63;
  const int xcd = blockIdx.x & 7, local = blockIdx.x >> 3;
  const int mt = xcd * 32 + (local >> 3), nt = local & 7;
  const int m0 = mt * 128, n0 = nt * 128;
  const int wm = wave & 1, wn = wave >> 1;

  f32x4 acc[4][4] = {};

  const int srow = lane >> 2;
  const int schunk = ((lane & 3) ^ ((srow >> 1) & 3)) * 8;  // swizzled source chunk

  for (int kt = 0; kt < D_IN / 32; ++kt) {
    const int k0 = kt * 32;
    __syncthreads();
    #pragma unroll
    for (int s0 = 0; s0 < 2; ++s0) {
      const int s = wave + s0 * 4;
      const unsigned short* ga = A + (size_t)(m0 + s * 16 + srow) * D_IN + k0 + schunk;
      __builtin_amdgcn_global_load_lds(
          (const __attribute__((address_space(1))) void*)ga,
          (__attribute__((address_space(3))) void*)(lA + s * 512), 16, 0, 0);
      const unsigned short* gb = Bt + (size_t)(n0 + s * 16 + srow) * D_IN + k0 + schunk;
      __builtin_amdgcn_global_load_lds(
          (const __attribute__((address_space(1))) void*)gb,
          (__attribute__((address_space(3))) void*)(lB + s * 512), 16, 0, 0);
    }
    __syncthreads();

    short8 af[4], bfr[4];
    const int rsel = lane & 15;
    const int q = lane >> 4;
    const int koff = (q ^ ((rsel >> 1) & 3)) * 8;
    #pragma unroll
    for (int tm = 0; tm < 4; tm++)
      af[tm] = *(const short8*)&lA[(wm * 64 + tm * 16 + rsel) * 32 + koff];
    #pragma unroll
    for (int tn = 0; tn < 4; tn++)
      bfr[tn] = *(const short8*)&lB[(wn * 64 + tn * 16 + rsel) * 32 + koff];
    #pragma unroll
    for (int tm = 0; tm < 4; tm++)
      #pragma unroll
      for (int tn = 0; tn < 4; tn++)
        acc[tm][tn] = __builtin_amdgcn_mfma_f32_16x16x32_bf16(
            af[tm], bfr[tn], acc[tm][tn], 0, 0, 0);
  }

  // C/D layout col=lane&15, row=(lane>>4)*4+reg  [m89-verified]
  const int lrow = (lane >> 4) * 4, lcol = lane & 15;
  #pragma unroll
  for (int tm = 0; tm < 4; tm++)
    #pragma unroll
    for (int tn = 0; tn < 4; tn++)
      #pragma unroll
      for (int r = 0; r < 4; r++) {
        const int row = m0 + wm * 64 + tm * 16 + lrow + r;
        const int col = n0 + wn * 64 + tn * 16 + lcol;
        C[(size_t)row * N_COL + col] = f2bf_rne(acc[tm][tn][r]);
      }
}

// ---------------------------------------------------------------------------
// s1q: strip sums of uhat over j (routing iter-1 up to a scale; squash is
// scale-invariant so the 1/16 is dropped).  Block = (b, s): sums 64 j's.
// S1q[b][s][n], n covered by 256 threads x ushort4 (8B/lane, coalesced rows).
// ---------------------------------------------------------------------------
__global__ __launch_bounds__(256) void s1q(
    const unsigned short* __restrict__ uhat, float* __restrict__ S1q) {
  const int t = threadIdx.x;
  const int b = blockIdx.x >> 3, s = blockIdx.x & 7;
  const unsigned short* up =
      uhat + (size_t)(b * N_IN + s * 64) * N_COL + t * 4;
  float4 a = make_float4(0.f, 0.f, 0.f, 0.f);
  #pragma unroll 8
  for (int j = 0; j < 64; ++j, up += N_COL) {
    const uint2 d = *(const uint2*)up;
    a.x += bf2f(d.x & 0xffffu);
    a.y += __uint_as_float(d.x & 0xffff0000u);
    a.z += bf2f(d.y & 0xffffu);
    a.w += __uint_as_float(d.y & 0xffff0000u);
  }
  *(float4*)&S1q[(size_t)blockIdx.x * 1024 + t * 4] = a;
}

// ---------------------------------------------------------------------------
// Routing iteration: block=(b,jt4).  Phase A (redundant, cheap): sum nstrips
// 1024-float strips of Vin -> s, squash -> v.  Phase B: wave w handles
// jt=jt4*4+w (8 j's); lane l holds uhat[b, i=l>>2, j, k=(l&3)*16..+16];
// b_i dot via quad shuffles; softmax over i (no max-subtract, |b| bounded);
// accumulate c*u; 4-wave LDS reduce -> Pout[blockIdx][i*64+k].
// ---------------------------------------------------------------------------
__global__ __launch_bounds__(256) void route_mid(
    const unsigned short* __restrict__ uhat,
    const float* __restrict__ Vin,
    float* __restrict__ Pout,
    const int nstrips) {
  __shared__ float sq[16 * 68];
  __shared__ float red[4][1024];
  const int t = threadIdx.x;
  const int w = t >> 6, lane = t & 63;
  const int b = blockIdx.x >> 4, jt4 = blockIdx.x & 15;
  const int jt = jt4 * 4 + w;
  const int i_l = lane >> 2, c4 = lane & 3;

  float4 v4 = make_float4(0.f, 0.f, 0.f, 0.f);
  for (int s = 0; s < nstrips; ++s) {
    const float4 ps = *(const float4*)&Vin[((size_t)b * nstrips + s) * 1024 + t * 4];
    v4.x += ps.x; v4.y += ps.y; v4.z += ps.z; v4.w += ps.w;
  }
  float ss = v4.x * v4.x + v4.y * v4.y + v4.z * v4.z + v4.w * v4.w;
  #pragma unroll
  for (int d = 1; d < 16; d <<= 1) ss += __shfl_xor(ss, d);  // 16 lanes = one capsule
  const float inv = 1.f / sqrtf(ss + 1e-7f);
  const int oi = t >> 4, ok = (t & 15) * 4;
  *(float4*)&sq[oi * 68 + ok] =
      make_float4(v4.x * inv, v4.y * inv, v4.z * inv, v4.w * inv);
  __syncthreads();

  float pv[16];
  #pragma unroll
  for (int q = 0; q < 4; q++)
    *(float4*)&pv[q * 4] = *(const float4*)&sq[i_l * 68 + c4 * 16 + q * 4];

  float acc[16];
  #pragma unroll
  for (int q = 0; q < 16; q++) acc[q] = 0.f;

  const unsigned short* ub =
      uhat + (size_t)(b * N_IN + jt * 8) * N_COL + lane * 16;

  for (int jj = 0; jj < 8; ++jj, ub += N_COL) {
    const uint4 d0 = *(const uint4*)ub;
    const uint4 d1 = *(const uint4*)(ub + 8);
    float u[16];
    #define UNP(wd, o) { u[(o)] = bf2f((wd) & 0xffffu); u[(o)+1] = __uint_as_float((wd) & 0xffff0000u); }
    UNP(d0.x, 0) UNP(d0.y, 2) UNP(d0.z, 4) UNP(d0.w, 6)
    UNP(d1.x, 8) UNP(d1.y, 10) UNP(d1.z, 12) UNP(d1.w, 14)
    #undef UNP

    float dot = 0.f;
    #pragma unroll
    for (int q = 0; q < 16; q++) dot = fmaf(pv[q], u[q], dot);
    dot += __shfl_xor(dot, 1);
    dot += __shfl_xor(dot, 2);
    const float e = __expf(dot);
    float s = e;
    #pragma unroll
    for (int d = 4; d < 64; d <<= 1) s += __shfl_xor(s, d);
    const float c = e / s;
    #pragma unroll
    for (int q = 0; q < 16; q++) acc[q] = fmaf(c, u[q], acc[q]);
  }

  #pragma unroll
  for (int q = 0; q < 4; q++)
    *(float4*)&red[w][lane * 16 + q * 4] = make_float4(
        acc[q * 4 + 0], acc[q * 4 + 1], acc[q * 4 + 2], acc[q * 4 + 3]);
  __syncthreads();
  float4 s4 = make_float4(0.f, 0.f, 0.f, 0.f);
  #pragma unroll
  for (int ww = 0; ww < 4; ++ww) {
    const float4 r = *(const float4*)&red[ww][t * 4];
    s4.x += r.x; s4.y += r.y; s4.z += r.z; s4.w += r.w;
  }
  *(float4*)&Pout[(size_t)blockIdx.x * 1024 + t * 4] = s4;
}

// ---------------------------------------------------------------------------
__global__ __launch_bounds__(64) void route_last(
    const float* __restrict__ P, float* __restrict__ dst) {
  const int bi = blockIdx.x;
  const int k = threadIdx.x;
  const int b = bi >> 4, i = bi & 15;
  const float* p = P + (size_t)b * 16 * 1024 + i * 64 + k;
  float s = 0.f;
  #pragma unroll
  for (int tt = 0; tt < 16; ++tt) s += p[(size_t)tt * 1024];
  float ss = s * s;
  #pragma unroll
  for (int d = 1; d < 64; d <<= 1) ss += __shfl_xor(ss, d);
  dst[bi * 64 + k] = s / sqrtf(ss + 1e-7f);
}

// ---------------------------------------------------------------------------
extern "C" void kernel_launch(void* const* d_in, const int* in_sizes, int n_in,
                              void* d_out, int out_size, void* d_ws, size_t ws_size,
                              hipStream_t stream) {
  const float* x = (const float*)d_in[0];   // [64][512][1024] fp32
  const float* W = (const float*)d_in[1];   // [1][1024][1024] fp32
  float* out = (float*)d_out;               // [64][16][64] fp32

  char* ws = (char*)d_ws;
  unsigned short* Wt   = (unsigned short*)ws;                            // 0..2 MB
  unsigned short* uhat = (unsigned short*)(ws + (size_t)(2 << 20));      // 2..66 MB
  unsigned short* xb   = (unsigned short*)(ws + (size_t)66 * (1 << 20)); // 66..130 (dead after gemm)
  float* S1 = (float*)(ws + (size_t)130 * (1 << 20));                    // 130..132 MB
  float* P1 = (float*)(ws + (size_t)66 * (1 << 20));   // reuses dead xb
  float* P2 = (float*)(ws + (size_t)71 * (1 << 20));   // reuses dead xb

  prep<<<16384 + 1024, 256, 0, stream>>>(x, W, xb, Wt);
  gemm_uhat<<<2048, 256, 0, stream>>>(xb, Wt, uhat);
  s1q<<<512, 256, 0, stream>>>(uhat, S1);
  route_mid<<<1024, 256, 0, stream>>>(uhat, S1, P1, 8);   // routing iter 2
  route_mid<<<1024, 256, 0, stream>>>(uhat, P1, P2, 16);  // routing iter 3
  route_last<<<1024, 64, 0, stream>>>(P2, out);
}